// Round 4
// baseline (1823.525 us; speedup 1.0000x reference)
//
#include <hip/hip_runtime.h>

// Problem constants: V=50000 D=300 H=512 CO=100 B=64 S=32 W=128
// Sentences: B*S = 2048, tokens/sentence = 128.
//
// Conv: grid 4096 = 2048 sentences x 2 position-halves. Each block stages
// 68 rows (64 positions + 4 halo) x LDSK=304 bf16 = 41376B -> 3 blocks/CU
// -> 12 waves/CU (was 2 blocks/8 waves at 80KB). Per-half channel maxima are
// plain-stored to sentP[sid][half][304]; consumers fmax the two halves.
// k>=300 tail reads hit zero slack / next-row data; A is zero-padded there.

#define LDSK     304
#define LDSBYTES 41376            // 68*304*2 + 32B slack; covers row-67 tail reads

typedef __bf16   bf16x8 __attribute__((ext_vector_type(8)));
typedef float    f32x4  __attribute__((ext_vector_type(4)));
typedef _Float16 h2v    __attribute__((ext_vector_type(2)));

// ---------------- P1: conv weights -> MFMA A-matrix bf16 [1344][320] ----------------
// conv3 rows 0..335, conv4 336..783, conv5 784..1343.
// row = (cg*kc + j)*16 + t, channel = cg*16 + t (ch>=100 and k>=300 zero-padded).
__global__ void prep_convw(const float* __restrict__ w3, const float* __restrict__ w4,
                           const float* __restrict__ w5, __bf16* __restrict__ Aw) {
  int idx = blockIdx.x * 256 + threadIdx.x;
  if (idx >= 1344 * 320) return;
  int row = idx / 320, k = idx - row * 320;
  int kc, rr; const float* w;
  if (row < 336)      { kc = 3; rr = row;       w = w3; }
  else if (row < 784) { kc = 4; rr = row - 336; w = w4; }
  else                { kc = 5; rr = row - 784; w = w5; }
  int cgj = rr >> 4, t = rr & 15;
  int cg = cgj / kc, j = cgj - cg * kc;
  int ch = cg * 16 + t;
  float v = 0.f;
  if (ch < 100 && k < 300) v = w[(ch * kc + j) * 300 + k];
  Aw[idx] = (__bf16)v;
}

// ---------------- P2: W_hh -> 16B-load layout -------------------------------------------------
// Wq[dir][kq][tid] (uint4): x=pack(W[tid][4kq],W[tid][4kq+1]) y=pack(W[tid+256][4kq],..+1)
//                           z=pack(W[tid][4kq+2],..+3)        w=pack(W[tid+256][4kq+2],..+3)
__device__ __forceinline__ unsigned int packf16(float a, float b) {
  h2v h; h[0] = (_Float16)a; h[1] = (_Float16)b;
  return __builtin_bit_cast(unsigned int, h);
}
__global__ void prep_whh(const float* __restrict__ whf, const float* __restrict__ whb,
                         uint4* __restrict__ Wq) {
  int idx = blockIdx.x * 256 + threadIdx.x;
  if (idx >= 2 * 128 * 256) return;
  int dir = idx >> 15;
  int rem = idx & 32767;
  int kq = rem >> 8, tid = rem & 255;
  const float* W = dir ? whb : whf;
  const float* r0 = W + (size_t)tid * 512 + 4 * kq;
  const float* r1 = W + (size_t)(tid + 256) * 512 + 4 * kq;
  uint4 o;
  o.x = packf16(r0[0], r0[1]);
  o.y = packf16(r1[0], r1[1]);
  o.z = packf16(r0[2], r0[3]);
  o.w = packf16(r1[2], r1[3]);
  Wq[idx] = o;
}

// ---------------- conv chunk: NCG channel-groups, compile-time window KC ----------------------
template<int NCG, int KC>
__device__ __forceinline__ void conv_chunk(const __bf16* lds, const __bf16* __restrict__ Aw,
                                           int Rc, int cg0, const float* __restrict__ bias,
                                           int colbase, int pmax, int pbase,
                                           float* __restrict__ prow, int lane) {
  const int lrow = lane & 15, lk = (lane >> 4) * 8;
  f32x4 acc[NCG][4];
#pragma unroll
  for (int i = 0; i < NCG; ++i)
#pragma unroll
    for (int n = 0; n < 4; ++n) acc[i][n] = (f32x4){0.f, 0.f, 0.f, 0.f};

#pragma unroll
  for (int j = 0; j < KC; ++j) {           // j-shift baked into B-row reads
    const __bf16* bbase = lds + (lrow + j) * LDSK + lk;
#pragma unroll
    for (int ks = 0; ks < 10; ++ks) {      // K = 320 = 10 * 32
      bf16x8 bf[4];
#pragma unroll
      for (int nt = 0; nt < 4; ++nt)
        bf[nt] = *(const bf16x8*)(bbase + nt * (16 * LDSK) + ks * 32);
#pragma unroll
      for (int i = 0; i < NCG; ++i) {
        int arow = Rc + ((cg0 + i) * KC + j) * 16 + lrow;
        bf16x8 af = *(const bf16x8*)(Aw + (size_t)arow * 320 + ks * 32 + lk);
#pragma unroll
        for (int nt = 0; nt < 4; ++nt)
          acc[i][nt] = __builtin_amdgcn_mfma_f32_16x16x32_bf16(af, bf[nt], acc[i][nt], 0, 0, 0);
      }
    }
  }
  // epilogue: +bias, relu, mask invalid positions, partial max over this half's 64 positions
#pragma unroll
  for (int i = 0; i < NCG; ++i) {
    int chbase = (cg0 + i) * 16 + ((lane >> 4) * 4);
    float bv[4];
#pragma unroll
    for (int r = 0; r < 4; ++r) bv[r] = ((chbase + r) < 100) ? bias[chbase + r] : 0.f;
    float m[4] = {0.f, 0.f, 0.f, 0.f};
#pragma unroll
    for (int nt = 0; nt < 4; ++nt) {
      int p = pbase + nt * 16 + lrow;
      bool valid = (p <= pmax);
#pragma unroll
      for (int r = 0; r < 4; ++r) {
        float v = acc[i][nt][r] + bv[r];
        v = fmaxf(v, 0.f);
        if (!valid) v = 0.f;
        m[r] = fmaxf(m[r], v);
      }
    }
#pragma unroll
    for (int r = 0; r < 4; ++r) {
#pragma unroll
      for (int d = 1; d < 16; d <<= 1) m[r] = fmaxf(m[r], __shfl_xor(m[r], d, 64));
      int ch = chbase + r;
      if (lrow == 0 && ch < 100) prow[colbase + ch] = m[r];
    }
  }
}

// ---------------- K1: per-half conv+relu+maxpool -> sentP[2048][2][304] f32 -------------------
__global__ void __launch_bounds__(256, 3)
conv_kernel(const int* __restrict__ tok, const float* __restrict__ emb,
            const __bf16* __restrict__ Aw,
            const float* __restrict__ b3, const float* __restrict__ b4, const float* __restrict__ b5,
            float* __restrict__ sentP) {
  extern __shared__ __bf16 lds[];          // LDSBYTES (41376)
  const int bid = blockIdx.x, tid = threadIdx.x;
  const int sid = bid >> 1, half = bid & 1;
  for (int i = tid; i < LDSBYTES / 4; i += 256) ((unsigned int*)lds)[i] = 0u;
  __syncthreads();
  const int* t0 = tok + sid * 128 + half * 64;
  const int nrows = half ? 64 : 68;        // half 0 stages 4 real spill rows; half 1 has zero halo
  for (int i = tid; i < nrows * 75; i += 256) {
    int r = i / 75, q = i - r * 75;
    long tk = (long)t0[r];
    float4 v = *(const float4*)(emb + tk * 300L + q * 4);
    union { __bf16 h[4]; uint2 u; } pk;
    pk.h[0] = (__bf16)v.x; pk.h[1] = (__bf16)v.y; pk.h[2] = (__bf16)v.z; pk.h[3] = (__bf16)v.w;
    *(uint2*)(lds + r * LDSK + q * 4) = pk.u;
  }
  __syncthreads();
  const int wave = tid >> 6, lane = tid & 63;
  const int pbase = half * 64;
  float* prow = sentP + (size_t)(sid * 2 + half) * 304;
  // static worklist: R3=0 R4=336 R5=784 ; pmax = 128-kc ; per-wave MFMA ~840-880
  switch (wave) {
    case 0:
      conv_chunk<3, 5>(lds, Aw, 784, 0, b5, 200, 123, pbase, prow, lane);
      conv_chunk<2, 3>(lds, Aw,   0, 0, b3,   0, 125, pbase, prow, lane);
      break;
    case 1:
      conv_chunk<3, 5>(lds, Aw, 784, 3, b5, 200, 123, pbase, prow, lane);
      conv_chunk<2, 3>(lds, Aw,   0, 2, b3,   0, 125, pbase, prow, lane);
      break;
    case 2:
      conv_chunk<1, 5>(lds, Aw, 784, 6, b5, 200, 123, pbase, prow, lane);
      conv_chunk<3, 4>(lds, Aw, 336, 0, b4, 100, 124, pbase, prow, lane);
      conv_chunk<1, 3>(lds, Aw,   0, 4, b3,   0, 125, pbase, prow, lane);
      break;
    default:
      conv_chunk<3, 4>(lds, Aw, 336, 3, b4, 100, 124, pbase, prow, lane);
      conv_chunk<1, 4>(lds, Aw, 336, 6, b4, 100, 124, pbase, prow, lane);
      conv_chunk<2, 3>(lds, Aw,   0, 5, b3,   0, 125, pbase, prow, lane);
      break;
  }
}

// ---------------- K2: fused XI = max(sentP)@proj^T+pb ; G = XI@[w_ih_f;w_ih_b]^T + biases -----
__global__ void xig_kernel(const float* __restrict__ sentP,
                           const float* __restrict__ pw, const float* __restrict__ pb,
                           const float* __restrict__ wf, const float* __restrict__ wb,
                           const float* __restrict__ bif, const float* __restrict__ bhf,
                           const float* __restrict__ bib, const float* __restrict__ bhb,
                           float* __restrict__ G) {
  __shared__ float s[8][300];
  __shared__ float xi[8][304];
  const int rb = blockIdx.x * 8, tid = threadIdx.x;
  for (int i = tid; i < 8 * 300; i += 256) {
    int r = i / 300, c = i - r * 300;
    const float* p2 = sentP + (size_t)(rb + r) * 608;
    s[r][c] = fmaxf(p2[c], p2[304 + c]);
  }
  __syncthreads();
  for (int o = tid; o < 300; o += 256) {
    const float* w = pw + o * 300;
    float bvv = pb[o];
    float a[8];
#pragma unroll
    for (int r = 0; r < 8; ++r) a[r] = bvv;
    for (int k = 0; k < 300; k += 4) {
      float4 wv = *(const float4*)(w + k);
#pragma unroll
      for (int r = 0; r < 8; ++r)
        a[r] += wv.x * s[r][k] + wv.y * s[r][k + 1] + wv.z * s[r][k + 2] + wv.w * s[r][k + 3];
    }
#pragma unroll
    for (int r = 0; r < 8; ++r) xi[r][o] = a[r];
  }
  __syncthreads();
  for (int o = tid; o < 1024; o += 256) {
    int dir = o >> 9, oo = o & 511;
    const float* w = (dir ? wb : wf) + oo * 300;
    float bvv = dir ? (bib[oo] + bhb[oo]) : (bif[oo] + bhf[oo]);
    float a[8];
#pragma unroll
    for (int r = 0; r < 8; ++r) a[r] = bvv;
    for (int k = 0; k < 300; k += 4) {
      float4 wv = *(const float4*)(w + k);
#pragma unroll
      for (int r = 0; r < 8; ++r)
        a[r] += wv.x * xi[r][k] + wv.y * xi[r][k + 1] + wv.z * xi[r][k + 2] + wv.w * xi[r][k + 3];
    }
#pragma unroll
    for (int r = 0; r < 8; ++r) G[(rb + r) * 1024 + o] = a[r];
  }
}

// ---------------- K3: h0 = sent[:,0,:] @ init_w^T + init_b  [64][512] ------------------------
__global__ void h0_kernel(const float* __restrict__ sentP, const float* __restrict__ iw,
                          const float* __restrict__ ib, float* __restrict__ h0) {
  __shared__ float s[8][300];
  const int bb = blockIdx.x * 8, tid = threadIdx.x;
  for (int i = tid; i < 8 * 300; i += 256) {
    int r = i / 300, c = i - r * 300;
    const float* p2 = sentP + (size_t)((bb + r) * 32) * 608;
    s[r][c] = fmaxf(p2[c], p2[304 + c]);
  }
  __syncthreads();
  for (int o = tid; o < 512; o += 256) {
    const float* w = iw + o * 300;
    float bvv = ib[o];
    float a[8];
#pragma unroll
    for (int r = 0; r < 8; ++r) a[r] = bvv;
    for (int k = 0; k < 300; k += 4) {
      float4 wv = *(const float4*)(w + k);
#pragma unroll
      for (int r = 0; r < 8; ++r)
        a[r] += wv.x * s[r][k] + wv.y * s[r][k + 1] + wv.z * s[r][k + 2] + wv.w * s[r][k + 3];
    }
#pragma unroll
    for (int r = 0; r < 8; ++r) h0[(bb + r) * 512 + o] = a[r];
  }
}

// ---------------- K4: persistent RNN, one block per (dir, batch) chain ------------------------
#if __has_builtin(__builtin_amdgcn_fdot2)
#define FDOT2(a, b, c) __builtin_amdgcn_fdot2((a), (b), (c), false)
#else
static __device__ __forceinline__ float FDOT2(h2v a, h2v b, float c) {
  return c + (float)a[0] * (float)b[0] + (float)a[1] * (float)b[1];
}
#endif
__device__ __forceinline__ h2v as_h2(unsigned int u) { return __builtin_bit_cast(h2v, u); }

__global__ void __launch_bounds__(256)
rnn_kernel(const uint4* __restrict__ Wq, const float* __restrict__ G,
           const float* __restrict__ h0, float* __restrict__ H) {
  const int blk = blockIdx.x, tid = threadIdx.x;
  const int dir = blk >> 6, b = blk & 63;
  __shared__ float hs[512];
  __shared__ uint2 h2p[128];
  for (int i = tid; i < 512; i += 256) hs[i] = h0[b * 512 + i];
  __syncthreads();
  const uint4* W = Wq + (size_t)dir * (128 * 256);
  for (int t = 0; t < 32; ++t) {
    { h2v hh; hh[0] = (_Float16)hs[2 * tid]; hh[1] = (_Float16)hs[2 * tid + 1];
      ((unsigned int*)h2p)[tid] = __builtin_bit_cast(unsigned int, hh); }
    __syncthreads();
    const float* g = G + ((size_t)(b * 32 + t)) * 1024 + dir * 512;
    // 4 split accumulators per output -> dependency chain 256 -> 64
    float s0[4], s1[4];
    s0[0] = g[tid]; s1[0] = g[tid + 256];
    s0[1] = s0[2] = s0[3] = 0.f;
    s1[1] = s1[2] = s1[3] = 0.f;
#pragma unroll 2
    for (int kb = 0; kb < 32; ++kb) {
#pragma unroll
      for (int u = 0; u < 4; ++u) {
        int kq = kb * 4 + u;
        uint4 wv = W[kq * 256 + tid];
        uint2 hp = h2p[kq];
        h2v p = as_h2(hp.x), q = as_h2(hp.y);
        s0[u] = FDOT2(as_h2(wv.x), p, s0[u]);
        s1[u] = FDOT2(as_h2(wv.y), p, s1[u]);
        s0[u] = FDOT2(as_h2(wv.z), q, s0[u]);
        s1[u] = FDOT2(as_h2(wv.w), q, s1[u]);
      }
    }
    float a0 = (s0[0] + s0[1]) + (s0[2] + s0[3]);
    float a1 = (s1[0] + s1[1]) + (s1[2] + s1[3]);
    __syncthreads();
    float n0 = tanhf(a0), n1 = tanhf(a1);
    hs[tid] = n0; hs[tid + 256] = n1;
    float* Ht = H + ((size_t)((dir * 64 + b) * 32 + t)) * 512;
    Ht[tid] = n0; Ht[tid + 256] = n1;
    __syncthreads();
  }
}

// ---------------- K5: preds = [hf;hb] @ cls_w^T + cls_b -> out[64][32][5] ---------------------
__global__ void pred_kernel(const float* __restrict__ H, const float* __restrict__ cw,
                            const float* __restrict__ cb, float* __restrict__ out) {
  const int bt = blockIdx.x;            // b*32 + t
  const int lane = threadIdx.x;         // 64
  const int b = bt >> 5, t = bt & 31;
  const float* hf = H + ((size_t)(b * 32 + t)) * 512;
  const float* hb = H + ((size_t)((64 + b) * 32 + t)) * 512;
  for (int c = 0; c < 5; ++c) {
    const float* w = cw + c * 1024;
    float a = 0.f;
    for (int o = lane; o < 512; o += 64) a += w[o] * hf[o] + w[512 + o] * hb[o];
#pragma unroll
    for (int d = 32; d; d >>= 1) a += __shfl_down(a, d, 64);
    if (lane == 0) out[bt * 5 + c] = a + cb[c];
  }
}

// ------------------------------------------------------------------------------------------------
extern "C" void kernel_launch(void* const* d_in, const int* in_sizes, int n_in,
                              void* d_out, int out_size, void* d_ws, size_t ws_size,
                              hipStream_t stream) {
  const int*   tok  = (const int*)d_in[0];
  const float* emb  = (const float*)d_in[1];
  const float* w3   = (const float*)d_in[2];
  const float* b3   = (const float*)d_in[3];
  const float* w4   = (const float*)d_in[4];
  const float* b4   = (const float*)d_in[5];
  const float* w5   = (const float*)d_in[6];
  const float* b5   = (const float*)d_in[7];
  const float* pw   = (const float*)d_in[8];
  const float* pb   = (const float*)d_in[9];
  const float* iw   = (const float*)d_in[10];
  const float* ib   = (const float*)d_in[11];
  const float* wihf = (const float*)d_in[12];
  const float* whhf = (const float*)d_in[13];
  const float* bihf = (const float*)d_in[14];
  const float* bhhf = (const float*)d_in[15];
  const float* wihb = (const float*)d_in[16];
  const float* whhb = (const float*)d_in[17];
  const float* bihb = (const float*)d_in[18];
  const float* bhhb = (const float*)d_in[19];
  const float* cw   = (const float*)d_in[20];
  const float* cb   = (const float*)d_in[21];
  float* out = (float*)d_out;

  char* ws = (char*)d_ws;
  __bf16* Aw    = (__bf16*)(ws);                        //  0MB: 860 KB
  uint4* Wq     = (uint4*)(ws +  1u * 1024 * 1024);     //  1MB: 1 MB
  float* sentP  = (float*)(ws +  2u * 1024 * 1024);     //  2MB: 2048*608*4 = 4.98 MB
  float* G      = (float*)(ws +  8u * 1024 * 1024);     //  8MB: 8 MB
  float* h0     = (float*)(ws + 16u * 1024 * 1024);     // 16MB: 128 KB
  float* H      = (float*)(ws + 17u * 1024 * 1024);     // 17MB: 16 MB (end 33MB)

  prep_convw<<<1680, 256, 0, stream>>>(w3, w4, w5, Aw);
  prep_whh<<<256, 256, 0, stream>>>(whhf, whhb, Wq);

  conv_kernel<<<4096, 256, LDSBYTES, stream>>>(tok, emb, Aw, b3, b4, b5, sentP);

  xig_kernel<<<256, 256, 0, stream>>>(sentP, pw, pb, wihf, wihb, bihf, bhhf, bihb, bhhb, G);
  h0_kernel<<<8, 256, 0, stream>>>(sentP, iw, ib, h0);
  rnn_kernel<<<128, 256, 0, stream>>>(Wq, G, h0, H);
  pred_kernel<<<2048, 64, 0, stream>>>(H, cw, cb, out);
}

// Round 5
// 915.303 us; speedup vs baseline: 1.9923x; 1.9923x over previous
//
#include <hip/hip_runtime.h>

// Problem constants: V=50000 D=300 H=512 CO=100 B=64 S=32 W=128
// Sentences: B*S = 2048, tokens/sentence = 128.
//
// Conv: grid 4096 = 2048 sentences x 2 position-halves. Each block stages
// 68 rows (64 positions + 4 halo) x LDSK=304 bf16 = 41376B -> 3 blocks/CU
// -> 12 waves/CU. Inner loop is the R3-verified runtime-j structure (full
// unroll in R4 caused acc->scratch demotion: 1.4GB spill writes, 3.4x slower).
// Per-half channel maxima plain-stored to sentP[sid][half][304]; consumers
// fmax the two halves. k>=300 tail reads hit zero slack / next-row data; the
// A matrix is zero-padded there so those products contribute 0.

#define LDSK     304
#define LDSBYTES 41376            // 68*304*2 = 20688 elems; max read index 20687

typedef __bf16   bf16x8 __attribute__((ext_vector_type(8)));
typedef float    f32x4  __attribute__((ext_vector_type(4)));
typedef _Float16 h2v    __attribute__((ext_vector_type(2)));

// ---------------- P1: conv weights -> MFMA A-matrix bf16 [1344][320] ----------------
// conv3 rows 0..335, conv4 336..783, conv5 784..1343.
// row = (cg*kc + j)*16 + t, channel = cg*16 + t (ch>=100 and k>=300 zero-padded).
__global__ void prep_convw(const float* __restrict__ w3, const float* __restrict__ w4,
                           const float* __restrict__ w5, __bf16* __restrict__ Aw) {
  int idx = blockIdx.x * 256 + threadIdx.x;
  if (idx >= 1344 * 320) return;
  int row = idx / 320, k = idx - row * 320;
  int kc, rr; const float* w;
  if (row < 336)      { kc = 3; rr = row;       w = w3; }
  else if (row < 784) { kc = 4; rr = row - 336; w = w4; }
  else                { kc = 5; rr = row - 784; w = w5; }
  int cgj = rr >> 4, t = rr & 15;
  int cg = cgj / kc, j = cgj - cg * kc;
  int ch = cg * 16 + t;
  float v = 0.f;
  if (ch < 100 && k < 300) v = w[(ch * kc + j) * 300 + k];
  Aw[idx] = (__bf16)v;
}

// ---------------- P2: W_hh -> 16B-load layout -------------------------------------------------
// Wq[dir][kq][tid] (uint4): x=pack(W[tid][4kq],W[tid][4kq+1]) y=pack(W[tid+256][4kq],..+1)
//                           z=pack(W[tid][4kq+2],..+3)        w=pack(W[tid+256][4kq+2],..+3)
__device__ __forceinline__ unsigned int packf16(float a, float b) {
  h2v h; h[0] = (_Float16)a; h[1] = (_Float16)b;
  return __builtin_bit_cast(unsigned int, h);
}
__global__ void prep_whh(const float* __restrict__ whf, const float* __restrict__ whb,
                         uint4* __restrict__ Wq) {
  int idx = blockIdx.x * 256 + threadIdx.x;
  if (idx >= 2 * 128 * 256) return;
  int dir = idx >> 15;
  int rem = idx & 32767;
  int kq = rem >> 8, tid = rem & 255;
  const float* W = dir ? whb : whf;
  const float* r0 = W + (size_t)tid * 512 + 4 * kq;
  const float* r1 = W + (size_t)(tid + 256) * 512 + 4 * kq;
  uint4 o;
  o.x = packf16(r0[0], r0[1]);
  o.y = packf16(r1[0], r1[1]);
  o.z = packf16(r0[2], r0[3]);
  o.w = packf16(r1[2], r1[3]);
  Wq[idx] = o;
}

// ---------------- conv chunk: NCG channel-groups, RUNTIME window kc (R3 structure) ------------
template<int NCG>
__device__ __forceinline__ void conv_chunk(const __bf16* lds, const __bf16* __restrict__ Aw,
                                           int Rc, int kc, int cg0, const float* __restrict__ bias,
                                           int colbase, int pmax, int pbase,
                                           float* __restrict__ prow, int lane) {
  const int lrow = lane & 15, lk = (lane >> 4) * 8;
  f32x4 acc[NCG][4];
#pragma unroll
  for (int i = 0; i < NCG; ++i)
#pragma unroll
    for (int n = 0; n < 4; ++n) acc[i][n] = (f32x4){0.f, 0.f, 0.f, 0.f};

  for (int j = 0; j < kc; ++j) {           // runtime j: keeps body small, no spills
    const __bf16* bbase = lds + (lrow + j) * LDSK + lk;
#pragma unroll
    for (int ks = 0; ks < 10; ++ks) {      // K = 320 = 10 * 32
      bf16x8 bf[4];
#pragma unroll
      for (int nt = 0; nt < 4; ++nt)
        bf[nt] = *(const bf16x8*)(bbase + nt * (16 * LDSK) + ks * 32);
#pragma unroll
      for (int i = 0; i < NCG; ++i) {
        int arow = Rc + ((cg0 + i) * kc + j) * 16 + lrow;
        bf16x8 af = *(const bf16x8*)(Aw + (size_t)arow * 320 + ks * 32 + lk);
#pragma unroll
        for (int nt = 0; nt < 4; ++nt)
          acc[i][nt] = __builtin_amdgcn_mfma_f32_16x16x32_bf16(af, bf[nt], acc[i][nt], 0, 0, 0);
      }
    }
  }
  // epilogue: +bias, relu, mask invalid positions, partial max over this half's 64 positions
#pragma unroll
  for (int i = 0; i < NCG; ++i) {
    int chbase = (cg0 + i) * 16 + ((lane >> 4) * 4);
    float bv[4];
#pragma unroll
    for (int r = 0; r < 4; ++r) bv[r] = ((chbase + r) < 100) ? bias[chbase + r] : 0.f;
    float m[4] = {0.f, 0.f, 0.f, 0.f};
#pragma unroll
    for (int nt = 0; nt < 4; ++nt) {
      int p = pbase + nt * 16 + lrow;
      bool valid = (p <= pmax);
#pragma unroll
      for (int r = 0; r < 4; ++r) {
        float v = acc[i][nt][r] + bv[r];
        v = fmaxf(v, 0.f);
        if (!valid) v = 0.f;
        m[r] = fmaxf(m[r], v);
      }
    }
#pragma unroll
    for (int r = 0; r < 4; ++r) {
#pragma unroll
      for (int d = 1; d < 16; d <<= 1) m[r] = fmaxf(m[r], __shfl_xor(m[r], d, 64));
      int ch = chbase + r;
      if (lrow == 0 && ch < 100) prow[colbase + ch] = m[r];
    }
  }
}

// ---------------- K1: per-half conv+relu+maxpool -> sentP[2048][2][304] f32 -------------------
__global__ void __launch_bounds__(256, 3)
conv_kernel(const int* __restrict__ tok, const float* __restrict__ emb,
            const __bf16* __restrict__ Aw,
            const float* __restrict__ b3, const float* __restrict__ b4, const float* __restrict__ b5,
            float* __restrict__ sentP) {
  extern __shared__ __bf16 lds[];          // LDSBYTES (41376)
  const int bid = blockIdx.x, tid = threadIdx.x;
  const int sid = bid >> 1, half = bid & 1;
  for (int i = tid; i < LDSBYTES / 4; i += 256) ((unsigned int*)lds)[i] = 0u;
  __syncthreads();
  const int* t0 = tok + sid * 128 + half * 64;
  const int nrows = half ? 64 : 68;        // half 0 stages 4 real spill rows; half 1 zero halo
  for (int i = tid; i < nrows * 75; i += 256) {
    int r = i / 75, q = i - r * 75;
    long tk = (long)t0[r];
    float4 v = *(const float4*)(emb + tk * 300L + q * 4);
    union { __bf16 h[4]; uint2 u; } pk;
    pk.h[0] = (__bf16)v.x; pk.h[1] = (__bf16)v.y; pk.h[2] = (__bf16)v.z; pk.h[3] = (__bf16)v.w;
    *(uint2*)(lds + r * LDSK + q * 4) = pk.u;
  }
  __syncthreads();
  const int wave = tid >> 6, lane = tid & 63;
  const int pbase = half * 64;
  float* prow = sentP + (size_t)(sid * 2 + half) * 304;
  // static worklist: R3=0 R4=336 R5=784 ; pmax = 128-kc ; per-wave MFMA 840/840/800/880
  switch (wave) {
    case 0:
      conv_chunk<3>(lds, Aw, 784, 5, 0, b5, 200, 123, pbase, prow, lane);
      conv_chunk<2>(lds, Aw,   0, 3, 0, b3,   0, 125, pbase, prow, lane);
      break;
    case 1:
      conv_chunk<3>(lds, Aw, 784, 5, 3, b5, 200, 123, pbase, prow, lane);
      conv_chunk<2>(lds, Aw,   0, 3, 2, b3,   0, 125, pbase, prow, lane);
      break;
    case 2:
      conv_chunk<1>(lds, Aw, 784, 5, 6, b5, 200, 123, pbase, prow, lane);
      conv_chunk<3>(lds, Aw, 336, 4, 0, b4, 100, 124, pbase, prow, lane);
      conv_chunk<1>(lds, Aw,   0, 3, 4, b3,   0, 125, pbase, prow, lane);
      break;
    default:
      conv_chunk<3>(lds, Aw, 336, 4, 3, b4, 100, 124, pbase, prow, lane);
      conv_chunk<1>(lds, Aw, 336, 4, 6, b4, 100, 124, pbase, prow, lane);
      conv_chunk<2>(lds, Aw,   0, 3, 5, b3,   0, 125, pbase, prow, lane);
      break;
  }
}

// ---------------- K2: merged grid: blocks 0..255 = xig ; blocks 256..263 = h0 -----------------
// xig: XI = max(sentP)@proj^T+pb ; G = XI@[w_ih_f;w_ih_b]^T + (b_ih+b_hh)
// h0:  h0 = sent[:,0,:] @ init_w^T + init_b
__global__ void xigh0_kernel(const float* __restrict__ sentP,
                             const float* __restrict__ pw, const float* __restrict__ pb,
                             const float* __restrict__ wf, const float* __restrict__ wb,
                             const float* __restrict__ bif, const float* __restrict__ bhf,
                             const float* __restrict__ bib, const float* __restrict__ bhb,
                             const float* __restrict__ iw, const float* __restrict__ ib,
                             float* __restrict__ G, float* __restrict__ h0) {
  __shared__ float s[8][300];
  __shared__ float xi[8][304];
  const int tid = threadIdx.x;
  if (blockIdx.x < 256) {
    const int rb = blockIdx.x * 8;
    for (int i = tid; i < 8 * 300; i += 256) {
      int r = i / 300, c = i - r * 300;
      const float* p2 = sentP + (size_t)(rb + r) * 608;
      s[r][c] = fmaxf(p2[c], p2[304 + c]);
    }
    __syncthreads();
    for (int o = tid; o < 300; o += 256) {
      const float* w = pw + o * 300;
      float bvv = pb[o];
      float a[8];
#pragma unroll
      for (int r = 0; r < 8; ++r) a[r] = bvv;
      for (int k = 0; k < 300; k += 4) {
        float4 wv = *(const float4*)(w + k);
#pragma unroll
        for (int r = 0; r < 8; ++r)
          a[r] += wv.x * s[r][k] + wv.y * s[r][k + 1] + wv.z * s[r][k + 2] + wv.w * s[r][k + 3];
      }
#pragma unroll
      for (int r = 0; r < 8; ++r) xi[r][o] = a[r];
    }
    __syncthreads();
    for (int o = tid; o < 1024; o += 256) {
      int dir = o >> 9, oo = o & 511;
      const float* w = (dir ? wb : wf) + oo * 300;
      float bvv = dir ? (bib[oo] + bhb[oo]) : (bif[oo] + bhf[oo]);
      float a[8];
#pragma unroll
      for (int r = 0; r < 8; ++r) a[r] = bvv;
      for (int k = 0; k < 300; k += 4) {
        float4 wv = *(const float4*)(w + k);
#pragma unroll
        for (int r = 0; r < 8; ++r)
          a[r] += wv.x * xi[r][k] + wv.y * xi[r][k + 1] + wv.z * xi[r][k + 2] + wv.w * xi[r][k + 3];
      }
#pragma unroll
      for (int r = 0; r < 8; ++r) G[(rb + r) * 1024 + o] = a[r];
    }
  } else {
    const int bb = (blockIdx.x - 256) * 8;
    for (int i = tid; i < 8 * 300; i += 256) {
      int r = i / 300, c = i - r * 300;
      const float* p2 = sentP + (size_t)((bb + r) * 32) * 608;
      s[r][c] = fmaxf(p2[c], p2[304 + c]);
    }
    __syncthreads();
    for (int o = tid; o < 512; o += 256) {
      const float* w = iw + o * 300;
      float bvv = ib[o];
      float a[8];
#pragma unroll
      for (int r = 0; r < 8; ++r) a[r] = bvv;
      for (int k = 0; k < 300; k += 4) {
        float4 wv = *(const float4*)(w + k);
#pragma unroll
        for (int r = 0; r < 8; ++r)
          a[r] += wv.x * s[r][k] + wv.y * s[r][k + 1] + wv.z * s[r][k + 2] + wv.w * s[r][k + 3];
      }
#pragma unroll
      for (int r = 0; r < 8; ++r) h0[(bb + r) * 512 + o] = a[r];
    }
  }
}

// ---------------- K4: persistent RNN, one block per (dir, batch) chain ------------------------
#if __has_builtin(__builtin_amdgcn_fdot2)
#define FDOT2(a, b, c) __builtin_amdgcn_fdot2((a), (b), (c), false)
#else
static __device__ __forceinline__ float FDOT2(h2v a, h2v b, float c) {
  return c + (float)a[0] * (float)b[0] + (float)a[1] * (float)b[1];
}
#endif
__device__ __forceinline__ h2v as_h2(unsigned int u) { return __builtin_bit_cast(h2v, u); }

__global__ void __launch_bounds__(256)
rnn_kernel(const uint4* __restrict__ Wq, const float* __restrict__ G,
           const float* __restrict__ h0, float* __restrict__ H) {
  const int blk = blockIdx.x, tid = threadIdx.x;
  const int dir = blk >> 6, b = blk & 63;
  __shared__ float hs[512];
  __shared__ uint2 h2p[128];
  for (int i = tid; i < 512; i += 256) hs[i] = h0[b * 512 + i];
  __syncthreads();
  const uint4* W = Wq + (size_t)dir * (128 * 256);
  for (int t = 0; t < 32; ++t) {
    { h2v hh; hh[0] = (_Float16)hs[2 * tid]; hh[1] = (_Float16)hs[2 * tid + 1];
      ((unsigned int*)h2p)[tid] = __builtin_bit_cast(unsigned int, hh); }
    __syncthreads();
    const float* g = G + ((size_t)(b * 32 + t)) * 1024 + dir * 512;
    // 4 split accumulators per output -> dependency chain 256 -> 64
    float s0[4], s1[4];
    s0[0] = g[tid]; s1[0] = g[tid + 256];
    s0[1] = s0[2] = s0[3] = 0.f;
    s1[1] = s1[2] = s1[3] = 0.f;
#pragma unroll 2
    for (int kb = 0; kb < 32; ++kb) {
#pragma unroll
      for (int u = 0; u < 4; ++u) {
        int kq = kb * 4 + u;
        uint4 wv = W[kq * 256 + tid];
        uint2 hp = h2p[kq];
        h2v p = as_h2(hp.x), q = as_h2(hp.y);
        s0[u] = FDOT2(as_h2(wv.x), p, s0[u]);
        s1[u] = FDOT2(as_h2(wv.y), p, s1[u]);
        s0[u] = FDOT2(as_h2(wv.z), q, s0[u]);
        s1[u] = FDOT2(as_h2(wv.w), q, s1[u]);
      }
    }
    float a0 = (s0[0] + s0[1]) + (s0[2] + s0[3]);
    float a1 = (s1[0] + s1[1]) + (s1[2] + s1[3]);
    __syncthreads();
    float n0 = tanhf(a0), n1 = tanhf(a1);
    hs[tid] = n0; hs[tid + 256] = n1;
    float* Ht = H + ((size_t)((dir * 64 + b) * 32 + t)) * 512;
    Ht[tid] = n0; Ht[tid + 256] = n1;
    __syncthreads();
  }
}

// ---------------- K5: preds = [hf;hb] @ cls_w^T + cls_b -> out[64][32][5] ---------------------
__global__ void pred_kernel(const float* __restrict__ H, const float* __restrict__ cw,
                            const float* __restrict__ cb, float* __restrict__ out) {
  const int bt = blockIdx.x;            // b*32 + t
  const int lane = threadIdx.x;         // 64
  const int b = bt >> 5, t = bt & 31;
  const float* hf = H + ((size_t)(b * 32 + t)) * 512;
  const float* hb = H + ((size_t)((64 + b) * 32 + t)) * 512;
  for (int c = 0; c < 5; ++c) {
    const float* w = cw + c * 1024;
    float a = 0.f;
    for (int o = lane; o < 512; o += 64) a += w[o] * hf[o] + w[512 + o] * hb[o];
#pragma unroll
    for (int d = 32; d; d >>= 1) a += __shfl_down(a, d, 64);
    if (lane == 0) out[bt * 5 + c] = a + cb[c];
  }
}

// ------------------------------------------------------------------------------------------------
extern "C" void kernel_launch(void* const* d_in, const int* in_sizes, int n_in,
                              void* d_out, int out_size, void* d_ws, size_t ws_size,
                              hipStream_t stream) {
  const int*   tok  = (const int*)d_in[0];
  const float* emb  = (const float*)d_in[1];
  const float* w3   = (const float*)d_in[2];
  const float* b3   = (const float*)d_in[3];
  const float* w4   = (const float*)d_in[4];
  const float* b4   = (const float*)d_in[5];
  const float* w5   = (const float*)d_in[6];
  const float* b5   = (const float*)d_in[7];
  const float* pw   = (const float*)d_in[8];
  const float* pb   = (const float*)d_in[9];
  const float* iw   = (const float*)d_in[10];
  const float* ib   = (const float*)d_in[11];
  const float* wihf = (const float*)d_in[12];
  const float* whhf = (const float*)d_in[13];
  const float* bihf = (const float*)d_in[14];
  const float* bhhf = (const float*)d_in[15];
  const float* wihb = (const float*)d_in[16];
  const float* whhb = (const float*)d_in[17];
  const float* bihb = (const float*)d_in[18];
  const float* bhhb = (const float*)d_in[19];
  const float* cw   = (const float*)d_in[20];
  const float* cb   = (const float*)d_in[21];
  float* out = (float*)d_out;

  char* ws = (char*)d_ws;
  __bf16* Aw    = (__bf16*)(ws);                        //  0MB: 860 KB
  uint4* Wq     = (uint4*)(ws +  1u * 1024 * 1024);     //  1MB: 1 MB
  float* sentP  = (float*)(ws +  2u * 1024 * 1024);     //  2MB: 2048*608*4 = 4.98 MB
  float* G      = (float*)(ws +  8u * 1024 * 1024);     //  8MB: 8 MB
  float* h0     = (float*)(ws + 16u * 1024 * 1024);     // 16MB: 128 KB
  float* H      = (float*)(ws + 17u * 1024 * 1024);     // 17MB: 8.4 MB (end ~26MB)

  prep_convw<<<1680, 256, 0, stream>>>(w3, w4, w5, Aw);
  prep_whh<<<256, 256, 0, stream>>>(whhf, whhb, Wq);

  conv_kernel<<<4096, 256, LDSBYTES, stream>>>(tok, emb, Aw, b3, b4, b5, sentP);

  xigh0_kernel<<<264, 256, 0, stream>>>(sentP, pw, pb, wihf, wihb, bihf, bhhf, bihb, bhhb,
                                        iw, ib, G, h0);
  rnn_kernel<<<128, 256, 0, stream>>>(Wq, G, h0, H);
  pred_kernel<<<2048, 64, 0, stream>>>(H, cw, cb, out);
}

// Round 6
// 804.326 us; speedup vs baseline: 2.2671x; 1.1380x over previous
//
#include <hip/hip_runtime.h>

// Problem constants: V=50000 D=300 H=512 CO=100 B=64 S=32 W=128
// Sentences: B*S = 2048, tokens/sentence = 128.
//
// Conv (R6): 32x32x16 MFMA, one sentence per block. B-tile in LDS: 132 rows
// (128 tokens + 4 zero halo) x LDSK=304 bf16 = 80256 B -> 2 blocks/CU.
// A repacked to [group][ks][lane][8] so each fragment load is one coalesced
// 1KB segment (group = (conv,cg32,j), 48 groups, L2-resident 983 KB).
// Per (j,ks): 4 ds_read_b128 feed 8 MFMA (2 ch-groups x 4 pos-tiles).
// j-shift baked into B row reads; k>=300 and ch>=100 zero-padded in A.
// Lesson R4: runtime j-loop, moderate ks unroll only (full unroll -> spills).

#define LDSK     304
#define LDSBYTES 80256            // 132*304*2

typedef __bf16   bf16x8 __attribute__((ext_vector_type(8)));
typedef float    f32x16 __attribute__((ext_vector_type(16)));
typedef _Float16 h2v    __attribute__((ext_vector_type(2)));

// ---------------- P1: conv weights -> coalesced A layout ---------------------------------------
// Aw32[((g*20 + ks)*64 + lane)*8 + i] = W[ch=cg*32+(lane&31)][k=ks*16+(lane>>5)*8+i]
// g: conv3 g=cg*3+j (0..11); conv4 g=12+cg*4+j (12..27); conv5 g=28+cg*5+j (28..47).
__global__ void prep_convw(const float* __restrict__ w3, const float* __restrict__ w4,
                           const float* __restrict__ w5, __bf16* __restrict__ Aw32) {
  int idx = blockIdx.x * 256 + threadIdx.x;
  if (idx >= 48 * 20 * 64 * 8) return;
  int i    = idx & 7;
  int lane = (idx >> 3) & 63;
  int rem  = idx >> 9;            // g*20 + ks
  int ks   = rem % 20, g = rem / 20;
  int kc, cg, j; const float* w;
  if (g < 12)      { kc = 3; cg = g / 3;        j = g % 3;        w = w3; }
  else if (g < 28) { kc = 4; cg = (g - 12) / 4; j = (g - 12) % 4; w = w4; }
  else             { kc = 5; cg = (g - 28) / 5; j = (g - 28) % 5; w = w5; }
  int ch = cg * 32 + (lane & 31);
  int k  = ks * 16 + (lane >> 5) * 8 + i;
  float v = 0.f;
  if (ch < 100 && k < 300) v = w[(ch * kc + j) * 300 + k];
  Aw32[idx] = (__bf16)v;
}

// ---------------- P2: W_hh -> 16B-load layout -------------------------------------------------
__device__ __forceinline__ unsigned int packf16(float a, float b) {
  h2v h; h[0] = (_Float16)a; h[1] = (_Float16)b;
  return __builtin_bit_cast(unsigned int, h);
}
__global__ void prep_whh(const float* __restrict__ whf, const float* __restrict__ whb,
                         uint4* __restrict__ Wq) {
  int idx = blockIdx.x * 256 + threadIdx.x;
  if (idx >= 2 * 128 * 256) return;
  int dir = idx >> 15;
  int rem = idx & 32767;
  int kq = rem >> 8, tid = rem & 255;
  const float* W = dir ? whb : whf;
  const float* r0 = W + (size_t)tid * 512 + 4 * kq;
  const float* r1 = W + (size_t)(tid + 256) * 512 + 4 * kq;
  uint4 o;
  o.x = packf16(r0[0], r0[1]);
  o.y = packf16(r1[0], r1[1]);
  o.z = packf16(r0[2], r0[3]);
  o.w = packf16(r1[2], r1[3]);
  Wq[idx] = o;
}

// ---------------- conv chunk: 2 channel-groups (64 ch) x 4 pos-tiles, runtime kc --------------
__device__ __forceinline__ void conv_chunk32(const __bf16* lds, const __bf16* __restrict__ Aw32,
                                             int GB, int kc, int cg0,
                                             const float* __restrict__ bias,
                                             int colbase, int pmax,
                                             float* __restrict__ srow, int lane) {
  const int m32 = lane & 31, hi = lane >> 5;
  f32x16 acc[2][4];
#pragma unroll
  for (int i = 0; i < 2; ++i)
#pragma unroll
    for (int n = 0; n < 4; ++n)
#pragma unroll
      for (int e = 0; e < 16; ++e) acc[i][n][e] = 0.f;

  for (int j = 0; j < kc; ++j) {                     // runtime j: small body, no spills
    const __bf16* bbase = lds + (m32 + j) * LDSK + hi * 8;
    const __bf16* a0 = Aw32 + ((size_t)((GB + cg0 * kc + j) * 20) << 9) + lane * 8;
    const __bf16* a1 = Aw32 + ((size_t)((GB + (cg0 + 1) * kc + j) * 20) << 9) + lane * 8;
#pragma unroll 2
    for (int ks = 0; ks < 20; ++ks) {
      bf16x8 bf[4];
#pragma unroll
      for (int nt = 0; nt < 4; ++nt)
        bf[nt] = *(const bf16x8*)(bbase + nt * (32 * LDSK) + ks * 16);
      bf16x8 af0 = *(const bf16x8*)(a0 + (ks << 9));
      bf16x8 af1 = *(const bf16x8*)(a1 + (ks << 9));
#pragma unroll
      for (int nt = 0; nt < 4; ++nt)
        acc[0][nt] = __builtin_amdgcn_mfma_f32_32x32x16_bf16(af0, bf[nt], acc[0][nt], 0, 0, 0);
#pragma unroll
      for (int nt = 0; nt < 4; ++nt)
        acc[1][nt] = __builtin_amdgcn_mfma_f32_32x32x16_bf16(af1, bf[nt], acc[1][nt], 0, 0, 0);
    }
  }
  // epilogue: mask invalid positions, max over positions, then relu(max + bias).
  // C layout: col(position) = lane&31, row(channel-in-32) = (r&3) + 8*(r>>2) + 4*hi.
#pragma unroll
  for (int i = 0; i < 2; ++i) {
    float m[16];
#pragma unroll
    for (int r = 0; r < 16; ++r) m[r] = -3.0e38f;
#pragma unroll
    for (int nt = 0; nt < 4; ++nt) {
      int p = nt * 32 + m32;
      bool valid = (p <= pmax);
#pragma unroll
      for (int r = 0; r < 16; ++r)
        m[r] = fmaxf(m[r], valid ? acc[i][nt][r] : -3.0e38f);
    }
#pragma unroll
    for (int r = 0; r < 16; ++r) {
#pragma unroll
      for (int d = 1; d < 32; d <<= 1) m[r] = fmaxf(m[r], __shfl_xor(m[r], d, 64));
    }
    if (m32 == 0) {
#pragma unroll
      for (int r = 0; r < 16; ++r) {
        int ch = (cg0 + i) * 32 + (r & 3) + 8 * (r >> 2) + 4 * hi;
        if (ch < 100) srow[colbase + ch] = fmaxf(m[r] + bias[ch], 0.f);
      }
    }
  }
}

// ---------------- K1: per-sentence conv+relu+maxpool -> sent[2048][304] f32 -------------------
__global__ void __launch_bounds__(256, 2)
conv_kernel(const int* __restrict__ tok, const float* __restrict__ emb,
            const __bf16* __restrict__ Aw32,
            const float* __restrict__ b3, const float* __restrict__ b4, const float* __restrict__ b5,
            float* __restrict__ sent) {
  extern __shared__ __bf16 lds[];          // LDSBYTES (80256)
  const int sid = blockIdx.x, tid = threadIdx.x;
  for (int i = tid; i < LDSBYTES / 4; i += 256) ((unsigned int*)lds)[i] = 0u;
  __syncthreads();
  const int* t0 = tok + sid * 128;
  for (int i = tid; i < 128 * 75; i += 256) {       // 75 float4 per 300-dim embedding row
    int r = i / 75, q = i - r * 75;
    long tk = (long)t0[r];
    float4 v = *(const float4*)(emb + tk * 300L + q * 4);
    union { __bf16 h[4]; uint2 u; } pk;
    pk.h[0] = (__bf16)v.x; pk.h[1] = (__bf16)v.y; pk.h[2] = (__bf16)v.z; pk.h[3] = (__bf16)v.w;
    *(uint2*)(lds + r * LDSK + q * 4) = pk.u;
  }
  __syncthreads();
  const int wave = tid >> 6, lane = tid & 63;
  float* srow = sent + (size_t)sid * 304;
  // worklist: conv5 GB=28 (waves 0,1), conv4 GB=12 + conv3 GB=0 (waves 2,3)
  switch (wave) {
    case 0:
      conv_chunk32(lds, Aw32, 28, 5, 0, b5, 200, 123, srow, lane);
      break;
    case 1:
      conv_chunk32(lds, Aw32, 28, 5, 2, b5, 200, 123, srow, lane);
      break;
    case 2:
      conv_chunk32(lds, Aw32, 12, 4, 0, b4, 100, 124, srow, lane);
      conv_chunk32(lds, Aw32,  0, 3, 0, b3,   0, 125, srow, lane);
      break;
    default:
      conv_chunk32(lds, Aw32, 12, 4, 2, b4, 100, 124, srow, lane);
      conv_chunk32(lds, Aw32,  0, 3, 2, b3,   0, 125, srow, lane);
      break;
  }
}

// ---------------- K2: merged grid: blocks 0..255 = xig ; blocks 256..263 = h0 -----------------
__global__ void xigh0_kernel(const float* __restrict__ sent,
                             const float* __restrict__ pw, const float* __restrict__ pb,
                             const float* __restrict__ wf, const float* __restrict__ wb,
                             const float* __restrict__ bif, const float* __restrict__ bhf,
                             const float* __restrict__ bib, const float* __restrict__ bhb,
                             const float* __restrict__ iw, const float* __restrict__ ib,
                             float* __restrict__ G, float* __restrict__ h0) {
  __shared__ float s[8][300];
  __shared__ float xi[8][304];
  const int tid = threadIdx.x;
  if (blockIdx.x < 256) {
    const int rb = blockIdx.x * 8;
    for (int i = tid; i < 8 * 300; i += 256) {
      int r = i / 300, c = i - r * 300;
      s[r][c] = sent[(size_t)(rb + r) * 304 + c];
    }
    __syncthreads();
    for (int o = tid; o < 300; o += 256) {
      const float* w = pw + o * 300;
      float bvv = pb[o];
      float a[8];
#pragma unroll
      for (int r = 0; r < 8; ++r) a[r] = bvv;
      for (int k = 0; k < 300; k += 4) {
        float4 wv = *(const float4*)(w + k);
#pragma unroll
        for (int r = 0; r < 8; ++r)
          a[r] += wv.x * s[r][k] + wv.y * s[r][k + 1] + wv.z * s[r][k + 2] + wv.w * s[r][k + 3];
      }
#pragma unroll
      for (int r = 0; r < 8; ++r) xi[r][o] = a[r];
    }
    __syncthreads();
    for (int o = tid; o < 1024; o += 256) {
      int dir = o >> 9, oo = o & 511;
      const float* w = (dir ? wb : wf) + oo * 300;
      float bvv = dir ? (bib[oo] + bhb[oo]) : (bif[oo] + bhf[oo]);
      float a[8];
#pragma unroll
      for (int r = 0; r < 8; ++r) a[r] = bvv;
      for (int k = 0; k < 300; k += 4) {
        float4 wv = *(const float4*)(w + k);
#pragma unroll
        for (int r = 0; r < 8; ++r)
          a[r] += wv.x * xi[r][k] + wv.y * xi[r][k + 1] + wv.z * xi[r][k + 2] + wv.w * xi[r][k + 3];
      }
#pragma unroll
      for (int r = 0; r < 8; ++r) G[(rb + r) * 1024 + o] = a[r];
    }
  } else {
    const int bb = (blockIdx.x - 256) * 8;
    for (int i = tid; i < 8 * 300; i += 256) {
      int r = i / 300, c = i - r * 300;
      s[r][c] = sent[(size_t)((bb + r) * 32) * 304 + c];
    }
    __syncthreads();
    for (int o = tid; o < 512; o += 256) {
      const float* w = iw + o * 300;
      float bvv = ib[o];
      float a[8];
#pragma unroll
      for (int r = 0; r < 8; ++r) a[r] = bvv;
      for (int k = 0; k < 300; k += 4) {
        float4 wv = *(const float4*)(w + k);
#pragma unroll
        for (int r = 0; r < 8; ++r)
          a[r] += wv.x * s[r][k] + wv.y * s[r][k + 1] + wv.z * s[r][k + 2] + wv.w * s[r][k + 3];
      }
#pragma unroll
      for (int r = 0; r < 8; ++r) h0[(bb + r) * 512 + o] = a[r];
    }
  }
}

// ---------------- K4: persistent RNN, one block per (dir, batch) chain ------------------------
#if __has_builtin(__builtin_amdgcn_fdot2)
#define FDOT2(a, b, c) __builtin_amdgcn_fdot2((a), (b), (c), false)
#else
static __device__ __forceinline__ float FDOT2(h2v a, h2v b, float c) {
  return c + (float)a[0] * (float)b[0] + (float)a[1] * (float)b[1];
}
#endif
__device__ __forceinline__ h2v as_h2(unsigned int u) { return __builtin_bit_cast(h2v, u); }

__global__ void __launch_bounds__(256)
rnn_kernel(const uint4* __restrict__ Wq, const float* __restrict__ G,
           const float* __restrict__ h0, float* __restrict__ H) {
  const int blk = blockIdx.x, tid = threadIdx.x;
  const int dir = blk >> 6, b = blk & 63;
  __shared__ float hs[512];
  __shared__ uint2 h2p[128];
  for (int i = tid; i < 512; i += 256) hs[i] = h0[b * 512 + i];
  __syncthreads();
  const uint4* W = Wq + (size_t)dir * (128 * 256);
  for (int t = 0; t < 32; ++t) {
    { h2v hh; hh[0] = (_Float16)hs[2 * tid]; hh[1] = (_Float16)hs[2 * tid + 1];
      ((unsigned int*)h2p)[tid] = __builtin_bit_cast(unsigned int, hh); }
    __syncthreads();
    const float* g = G + ((size_t)(b * 32 + t)) * 1024 + dir * 512;
    float s0[4], s1[4];
    s0[0] = g[tid]; s1[0] = g[tid + 256];
    s0[1] = s0[2] = s0[3] = 0.f;
    s1[1] = s1[2] = s1[3] = 0.f;
#pragma unroll 2
    for (int kb = 0; kb < 32; ++kb) {
#pragma unroll
      for (int u = 0; u < 4; ++u) {
        int kq = kb * 4 + u;
        uint4 wv = W[kq * 256 + tid];
        uint2 hp = h2p[kq];
        h2v p = as_h2(hp.x), q = as_h2(hp.y);
        s0[u] = FDOT2(as_h2(wv.x), p, s0[u]);
        s1[u] = FDOT2(as_h2(wv.y), p, s1[u]);
        s0[u] = FDOT2(as_h2(wv.z), q, s0[u]);
        s1[u] = FDOT2(as_h2(wv.w), q, s1[u]);
      }
    }
    float a0 = (s0[0] + s0[1]) + (s0[2] + s0[3]);
    float a1 = (s1[0] + s1[1]) + (s1[2] + s1[3]);
    __syncthreads();
    float n0 = tanhf(a0), n1 = tanhf(a1);
    hs[tid] = n0; hs[tid + 256] = n1;
    float* Ht = H + ((size_t)((dir * 64 + b) * 32 + t)) * 512;
    Ht[tid] = n0; Ht[tid + 256] = n1;
    __syncthreads();
  }
}

// ---------------- K5: preds = [hf;hb] @ cls_w^T + cls_b -> out[64][32][5] ---------------------
__global__ void pred_kernel(const float* __restrict__ H, const float* __restrict__ cw,
                            const float* __restrict__ cb, float* __restrict__ out) {
  const int bt = blockIdx.x;            // b*32 + t
  const int lane = threadIdx.x;         // 64
  const int b = bt >> 5, t = bt & 31;
  const float* hf = H + ((size_t)(b * 32 + t)) * 512;
  const float* hb = H + ((size_t)((64 + b) * 32 + t)) * 512;
  for (int c = 0; c < 5; ++c) {
    const float* w = cw + c * 1024;
    float a = 0.f;
    for (int o = lane; o < 512; o += 64) a += w[o] * hf[o] + w[512 + o] * hb[o];
#pragma unroll
    for (int d = 32; d; d >>= 1) a += __shfl_down(a, d, 64);
    if (lane == 0) out[bt * 5 + c] = a + cb[c];
  }
}

// ------------------------------------------------------------------------------------------------
extern "C" void kernel_launch(void* const* d_in, const int* in_sizes, int n_in,
                              void* d_out, int out_size, void* d_ws, size_t ws_size,
                              hipStream_t stream) {
  const int*   tok  = (const int*)d_in[0];
  const float* emb  = (const float*)d_in[1];
  const float* w3   = (const float*)d_in[2];
  const float* b3   = (const float*)d_in[3];
  const float* w4   = (const float*)d_in[4];
  const float* b4   = (const float*)d_in[5];
  const float* w5   = (const float*)d_in[6];
  const float* b5   = (const float*)d_in[7];
  const float* pw   = (const float*)d_in[8];
  const float* pb   = (const float*)d_in[9];
  const float* iw   = (const float*)d_in[10];
  const float* ib   = (const float*)d_in[11];
  const float* wihf = (const float*)d_in[12];
  const float* whhf = (const float*)d_in[13];
  const float* bihf = (const float*)d_in[14];
  const float* bhhf = (const float*)d_in[15];
  const float* wihb = (const float*)d_in[16];
  const float* whhb = (const float*)d_in[17];
  const float* bihb = (const float*)d_in[18];
  const float* bhhb = (const float*)d_in[19];
  const float* cw   = (const float*)d_in[20];
  const float* cb   = (const float*)d_in[21];
  float* out = (float*)d_out;

  char* ws = (char*)d_ws;
  __bf16* Aw32  = (__bf16*)(ws);                        //  0MB: 983 KB
  uint4* Wq     = (uint4*)(ws +  1u * 1024 * 1024);     //  1MB: 1 MB
  float* sent   = (float*)(ws +  2u * 1024 * 1024);     //  2MB: 2048*304*4 = 2.49 MB
  float* G      = (float*)(ws +  8u * 1024 * 1024);     //  8MB: 8 MB
  float* h0     = (float*)(ws + 16u * 1024 * 1024);     // 16MB: 128 KB
  float* H      = (float*)(ws + 17u * 1024 * 1024);     // 17MB: 8.4 MB (end ~26MB)

  prep_convw<<<1920, 256, 0, stream>>>(w3, w4, w5, Aw32);
  prep_whh<<<256, 256, 0, stream>>>(whhf, whhb, Wq);

  hipFuncSetAttribute(reinterpret_cast<const void*>(conv_kernel),
                      hipFuncAttributeMaxDynamicSharedMemorySize, LDSBYTES);
  conv_kernel<<<2048, 256, LDSBYTES, stream>>>(tok, emb, Aw32, b3, b4, b5, sent);

  xigh0_kernel<<<264, 256, 0, stream>>>(sent, pw, pb, wihf, wihb, bihf, bhhf, bihb, bhhb,
                                        iw, ib, G, h0);
  rnn_kernel<<<128, 256, 0, stream>>>(Wq, G, h0, H);
  pred_kernel<<<2048, 64, 0, stream>>>(H, cw, cb, out);
}

// Round 7
// 642.269 us; speedup vs baseline: 2.8392x; 1.2523x over previous
//
#include <hip/hip_runtime.h>

// Problem constants: V=50000 D=300 H=512 CO=100 B=64 S=32 W=128
// Sentences: B*S = 2048, tokens/sentence = 128.
//
// Conv (R7 = R6 + LDS XOR swizzle): 32x32x16 MFMA, one sentence per block.
// B-tile in LDS: 132 rows x LDSK=304 bf16, byte-swizzle ^((row&7)<<4) on both
// staging writes and fragment reads (m214-style fix: 32 lanes reading 32 rows
// at stride 608B were an 8-way bank-group conflict -> 16M conflict cycles in R6).
// +128B pad so ks=19/row-131 tail reads stay in owned (zeroed) LDS.
// A repacked to [group][ks][lane][8]: each fragment load = one coalesced 1KB
// segment, L2-resident (983KB). Per (j,ks): 4 ds_read_b128 feed 8 MFMA.
// k>=300 / ch>=100 zero-padded in A annihilate tail garbage in B.
// Lesson R4: runtime j-loop, moderate ks unroll only (full unroll -> spills).

#define LDSK     304
#define LDSROWB  608              // row stride bytes
#define LDSBYTES 80384            // 132*608 + 128 pad -> 2 blocks/CU (160.8KB/CU)

typedef __bf16   bf16x8 __attribute__((ext_vector_type(8)));
typedef float    f32x16 __attribute__((ext_vector_type(16)));
typedef _Float16 h2v    __attribute__((ext_vector_type(2)));

// ---------------- P1: conv weights -> coalesced A layout ---------------------------------------
// Aw32[((g*20 + ks)*64 + lane)*8 + i] = W[ch=cg*32+(lane&31)][k=ks*16+(lane>>5)*8+i]
// g: conv3 g=cg*3+j (0..11); conv4 g=12+cg*4+j (12..27); conv5 g=28+cg*5+j (28..47).
__global__ void prep_convw(const float* __restrict__ w3, const float* __restrict__ w4,
                           const float* __restrict__ w5, __bf16* __restrict__ Aw32) {
  int idx = blockIdx.x * 256 + threadIdx.x;
  if (idx >= 48 * 20 * 64 * 8) return;
  int i    = idx & 7;
  int lane = (idx >> 3) & 63;
  int rem  = idx >> 9;            // g*20 + ks
  int ks   = rem % 20, g = rem / 20;
  int kc, cg, j; const float* w;
  if (g < 12)      { kc = 3; cg = g / 3;        j = g % 3;        w = w3; }
  else if (g < 28) { kc = 4; cg = (g - 12) / 4; j = (g - 12) % 4; w = w4; }
  else             { kc = 5; cg = (g - 28) / 5; j = (g - 28) % 5; w = w5; }
  int ch = cg * 32 + (lane & 31);
  int k  = ks * 16 + (lane >> 5) * 8 + i;
  float v = 0.f;
  if (ch < 100 && k < 300) v = w[(ch * kc + j) * 300 + k];
  Aw32[idx] = (__bf16)v;
}

// ---------------- P2: W_hh -> 16B-load layout -------------------------------------------------
__device__ __forceinline__ unsigned int packf16(float a, float b) {
  h2v h; h[0] = (_Float16)a; h[1] = (_Float16)b;
  return __builtin_bit_cast(unsigned int, h);
}
__global__ void prep_whh(const float* __restrict__ whf, const float* __restrict__ whb,
                         uint4* __restrict__ Wq) {
  int idx = blockIdx.x * 256 + threadIdx.x;
  if (idx >= 2 * 128 * 256) return;
  int dir = idx >> 15;
  int rem = idx & 32767;
  int kq = rem >> 8, tid = rem & 255;
  const float* W = dir ? whb : whf;
  const float* r0 = W + (size_t)tid * 512 + 4 * kq;
  const float* r1 = W + (size_t)(tid + 256) * 512 + 4 * kq;
  uint4 o;
  o.x = packf16(r0[0], r0[1]);
  o.y = packf16(r1[0], r1[1]);
  o.z = packf16(r0[2], r0[3]);
  o.w = packf16(r1[2], r1[3]);
  Wq[idx] = o;
}

// ---------------- conv chunk: 2 channel-groups (64 ch) x 4 pos-tiles, runtime kc --------------
__device__ __forceinline__ void conv_chunk32(const char* ldsc, const __bf16* __restrict__ Aw32,
                                             int GB, int kc, int cg0,
                                             const float* __restrict__ bias,
                                             int colbase, int pmax,
                                             float* __restrict__ srow, int lane) {
  const int m32 = lane & 31, hi = lane >> 5;
  f32x16 acc[2][4];
#pragma unroll
  for (int i = 0; i < 2; ++i)
#pragma unroll
    for (int n = 0; n < 4; ++n)
#pragma unroll
      for (int e = 0; e < 16; ++e) acc[i][n][e] = 0.f;

  for (int j = 0; j < kc; ++j) {                     // runtime j: small body, no spills
    const int row0 = m32 + j;
    const int mask = (row0 & 7) << 4;                // nt*32 rows: (row&7) invariant
    const int rowbyte = row0 * LDSROWB + hi * 16;
    const __bf16* a0 = Aw32 + ((size_t)((GB + cg0 * kc + j) * 20) << 9) + lane * 8;
    const __bf16* a1 = Aw32 + ((size_t)((GB + (cg0 + 1) * kc + j) * 20) << 9) + lane * 8;
#pragma unroll 2
    for (int ks = 0; ks < 20; ++ks) {
      bf16x8 bf[4];
#pragma unroll
      for (int nt = 0; nt < 4; ++nt) {
        int addr = rowbyte + nt * (32 * LDSROWB) + ks * 32;
        bf[nt] = *(const bf16x8*)(ldsc + (addr ^ mask));
      }
      bf16x8 af0 = *(const bf16x8*)(a0 + (ks << 9));
      bf16x8 af1 = *(const bf16x8*)(a1 + (ks << 9));
#pragma unroll
      for (int nt = 0; nt < 4; ++nt)
        acc[0][nt] = __builtin_amdgcn_mfma_f32_32x32x16_bf16(af0, bf[nt], acc[0][nt], 0, 0, 0);
#pragma unroll
      for (int nt = 0; nt < 4; ++nt)
        acc[1][nt] = __builtin_amdgcn_mfma_f32_32x32x16_bf16(af1, bf[nt], acc[1][nt], 0, 0, 0);
    }
  }
  // epilogue: mask invalid positions, max over positions, then relu(max + bias).
  // C layout: col(position) = lane&31, row(channel-in-32) = (r&3) + 8*(r>>2) + 4*hi.
#pragma unroll
  for (int i = 0; i < 2; ++i) {
    float m[16];
#pragma unroll
    for (int r = 0; r < 16; ++r) m[r] = -3.0e38f;
#pragma unroll
    for (int nt = 0; nt < 4; ++nt) {
      int p = nt * 32 + m32;
      bool valid = (p <= pmax);
#pragma unroll
      for (int r = 0; r < 16; ++r)
        m[r] = fmaxf(m[r], valid ? acc[i][nt][r] : -3.0e38f);
    }
#pragma unroll
    for (int r = 0; r < 16; ++r) {
#pragma unroll
      for (int d = 1; d < 32; d <<= 1) m[r] = fmaxf(m[r], __shfl_xor(m[r], d, 64));
    }
    if (m32 == 0) {
#pragma unroll
      for (int r = 0; r < 16; ++r) {
        int ch = (cg0 + i) * 32 + (r & 3) + 8 * (r >> 2) + 4 * hi;
        if (ch < 100) srow[colbase + ch] = fmaxf(m[r] + bias[ch], 0.f);
      }
    }
  }
}

// ---------------- K1: per-sentence conv+relu+maxpool -> sent[2048][304] f32 -------------------
__global__ void __launch_bounds__(256, 2)
conv_kernel(const int* __restrict__ tok, const float* __restrict__ emb,
            const __bf16* __restrict__ Aw32,
            const float* __restrict__ b3, const float* __restrict__ b4, const float* __restrict__ b5,
            float* __restrict__ sent) {
  extern __shared__ __bf16 lds[];          // LDSBYTES (80384)
  char* ldsc = (char*)lds;
  const int sid = blockIdx.x, tid = threadIdx.x;
  for (int i = tid; i < LDSBYTES / 4; i += 256) ((unsigned int*)lds)[i] = 0u;
  __syncthreads();
  const int* t0 = tok + sid * 128;
  for (int i = tid; i < 128 * 75; i += 256) {       // 75 float4 per 300-dim embedding row
    int r = i / 75, q = i - r * 75;
    long tk = (long)t0[r];
    float4 v = *(const float4*)(emb + tk * 300L + q * 4);
    union { __bf16 h[4]; uint2 u; } pk;
    pk.h[0] = (__bf16)v.x; pk.h[1] = (__bf16)v.y; pk.h[2] = (__bf16)v.z; pk.h[3] = (__bf16)v.w;
    int wb = (r * LDSROWB + q * 8) ^ ((r & 7) << 4);   // same swizzle as reads
    *(uint2*)(ldsc + wb) = pk.u;
  }
  __syncthreads();
  const int wave = tid >> 6, lane = tid & 63;
  float* srow = sent + (size_t)sid * 304;
  // worklist: conv5 GB=28 (waves 0,1), conv4 GB=12 + conv3 GB=0 (waves 2,3)
  switch (wave) {
    case 0:
      conv_chunk32(ldsc, Aw32, 28, 5, 0, b5, 200, 123, srow, lane);
      break;
    case 1:
      conv_chunk32(ldsc, Aw32, 28, 5, 2, b5, 200, 123, srow, lane);
      break;
    case 2:
      conv_chunk32(ldsc, Aw32, 12, 4, 0, b4, 100, 124, srow, lane);
      conv_chunk32(ldsc, Aw32,  0, 3, 0, b3,   0, 125, srow, lane);
      break;
    default:
      conv_chunk32(ldsc, Aw32, 12, 4, 2, b4, 100, 124, srow, lane);
      conv_chunk32(ldsc, Aw32,  0, 3, 2, b3,   0, 125, srow, lane);
      break;
  }
}

// ---------------- K2: merged grid: blocks 0..255 = xig ; blocks 256..263 = h0 -----------------
__global__ void xigh0_kernel(const float* __restrict__ sent,
                             const float* __restrict__ pw, const float* __restrict__ pb,
                             const float* __restrict__ wf, const float* __restrict__ wb,
                             const float* __restrict__ bif, const float* __restrict__ bhf,
                             const float* __restrict__ bib, const float* __restrict__ bhb,
                             const float* __restrict__ iw, const float* __restrict__ ib,
                             float* __restrict__ G, float* __restrict__ h0) {
  __shared__ float s[8][300];
  __shared__ float xi[8][304];
  const int tid = threadIdx.x;
  if (blockIdx.x < 256) {
    const int rb = blockIdx.x * 8;
    for (int i = tid; i < 8 * 300; i += 256) {
      int r = i / 300, c = i - r * 300;
      s[r][c] = sent[(size_t)(rb + r) * 304 + c];
    }
    __syncthreads();
    for (int o = tid; o < 300; o += 256) {
      const float* w = pw + o * 300;
      float bvv = pb[o];
      float a[8];
#pragma unroll
      for (int r = 0; r < 8; ++r) a[r] = bvv;
      for (int k = 0; k < 300; k += 4) {
        float4 wv = *(const float4*)(w + k);
#pragma unroll
        for (int r = 0; r < 8; ++r)
          a[r] += wv.x * s[r][k] + wv.y * s[r][k + 1] + wv.z * s[r][k + 2] + wv.w * s[r][k + 3];
      }
#pragma unroll
      for (int r = 0; r < 8; ++r) xi[r][o] = a[r];
    }
    __syncthreads();
    for (int o = tid; o < 1024; o += 256) {
      int dir = o >> 9, oo = o & 511;
      const float* w = (dir ? wb : wf) + oo * 300;
      float bvv = dir ? (bib[oo] + bhb[oo]) : (bif[oo] + bhf[oo]);
      float a[8];
#pragma unroll
      for (int r = 0; r < 8; ++r) a[r] = bvv;
      for (int k = 0; k < 300; k += 4) {
        float4 wv = *(const float4*)(w + k);
#pragma unroll
        for (int r = 0; r < 8; ++r)
          a[r] += wv.x * xi[r][k] + wv.y * xi[r][k + 1] + wv.z * xi[r][k + 2] + wv.w * xi[r][k + 3];
      }
#pragma unroll
      for (int r = 0; r < 8; ++r) G[(rb + r) * 1024 + o] = a[r];
    }
  } else {
    const int bb = (blockIdx.x - 256) * 8;
    for (int i = tid; i < 8 * 300; i += 256) {
      int r = i / 300, c = i - r * 300;
      s[r][c] = sent[(size_t)((bb + r) * 32) * 304 + c];
    }
    __syncthreads();
    for (int o = tid; o < 512; o += 256) {
      const float* w = iw + o * 300;
      float bvv = ib[o];
      float a[8];
#pragma unroll
      for (int r = 0; r < 8; ++r) a[r] = bvv;
      for (int k = 0; k < 300; k += 4) {
        float4 wv = *(const float4*)(w + k);
#pragma unroll
        for (int r = 0; r < 8; ++r)
          a[r] += wv.x * s[r][k] + wv.y * s[r][k + 1] + wv.z * s[r][k + 2] + wv.w * s[r][k + 3];
      }
#pragma unroll
      for (int r = 0; r < 8; ++r) h0[(bb + r) * 512 + o] = a[r];
    }
  }
}

// ---------------- K4: persistent RNN, one block per (dir, batch) chain ------------------------
#if __has_builtin(__builtin_amdgcn_fdot2)
#define FDOT2(a, b, c) __builtin_amdgcn_fdot2((a), (b), (c), false)
#else
static __device__ __forceinline__ float FDOT2(h2v a, h2v b, float c) {
  return c + (float)a[0] * (float)b[0] + (float)a[1] * (float)b[1];
}
#endif
__device__ __forceinline__ h2v as_h2(unsigned int u) { return __builtin_bit_cast(h2v, u); }

__global__ void __launch_bounds__(256)
rnn_kernel(const uint4* __restrict__ Wq, const float* __restrict__ G,
           const float* __restrict__ h0, float* __restrict__ H) {
  const int blk = blockIdx.x, tid = threadIdx.x;
  const int dir = blk >> 6, b = blk & 63;
  __shared__ float hs[512];
  __shared__ uint2 h2p[128];
  for (int i = tid; i < 512; i += 256) hs[i] = h0[b * 512 + i];
  __syncthreads();
  const uint4* W = Wq + (size_t)dir * (128 * 256);
  for (int t = 0; t < 32; ++t) {
    { h2v hh; hh[0] = (_Float16)hs[2 * tid]; hh[1] = (_Float16)hs[2 * tid + 1];
      ((unsigned int*)h2p)[tid] = __builtin_bit_cast(unsigned int, hh); }
    __syncthreads();
    const float* g = G + ((size_t)(b * 32 + t)) * 1024 + dir * 512;
    float s0[4], s1[4];
    s0[0] = g[tid]; s1[0] = g[tid + 256];
    s0[1] = s0[2] = s0[3] = 0.f;
    s1[1] = s1[2] = s1[3] = 0.f;
#pragma unroll 2
    for (int kb = 0; kb < 32; ++kb) {
#pragma unroll
      for (int u = 0; u < 4; ++u) {
        int kq = kb * 4 + u;
        uint4 wv = W[kq * 256 + tid];
        uint2 hp = h2p[kq];
        h2v p = as_h2(hp.x), q = as_h2(hp.y);
        s0[u] = FDOT2(as_h2(wv.x), p, s0[u]);
        s1[u] = FDOT2(as_h2(wv.y), p, s1[u]);
        s0[u] = FDOT2(as_h2(wv.z), q, s0[u]);
        s1[u] = FDOT2(as_h2(wv.w), q, s1[u]);
      }
    }
    float a0 = (s0[0] + s0[1]) + (s0[2] + s0[3]);
    float a1 = (s1[0] + s1[1]) + (s1[2] + s1[3]);
    __syncthreads();
    float n0 = tanhf(a0), n1 = tanhf(a1);
    hs[tid] = n0; hs[tid + 256] = n1;
    float* Ht = H + ((size_t)((dir * 64 + b) * 32 + t)) * 512;
    Ht[tid] = n0; Ht[tid + 256] = n1;
    __syncthreads();
  }
}

// ---------------- K5: preds = [hf;hb] @ cls_w^T + cls_b -> out[64][32][5] ---------------------
__global__ void pred_kernel(const float* __restrict__ H, const float* __restrict__ cw,
                            const float* __restrict__ cb, float* __restrict__ out) {
  const int bt = blockIdx.x;            // b*32 + t
  const int lane = threadIdx.x;         // 64
  const int b = bt >> 5, t = bt & 31;
  const float* hf = H + ((size_t)(b * 32 + t)) * 512;
  const float* hb = H + ((size_t)((64 + b) * 32 + t)) * 512;
  for (int c = 0; c < 5; ++c) {
    const float* w = cw + c * 1024;
    float a = 0.f;
    for (int o = lane; o < 512; o += 64) a += w[o] * hf[o] + w[512 + o] * hb[o];
#pragma unroll
    for (int d = 32; d; d >>= 1) a += __shfl_down(a, d, 64);
    if (lane == 0) out[bt * 5 + c] = a + cb[c];
  }
}

// ------------------------------------------------------------------------------------------------
extern "C" void kernel_launch(void* const* d_in, const int* in_sizes, int n_in,
                              void* d_out, int out_size, void* d_ws, size_t ws_size,
                              hipStream_t stream) {
  const int*   tok  = (const int*)d_in[0];
  const float* emb  = (const float*)d_in[1];
  const float* w3   = (const float*)d_in[2];
  const float* b3   = (const float*)d_in[3];
  const float* w4   = (const float*)d_in[4];
  const float* b4   = (const float*)d_in[5];
  const float* w5   = (const float*)d_in[6];
  const float* b5   = (const float*)d_in[7];
  const float* pw   = (const float*)d_in[8];
  const float* pb   = (const float*)d_in[9];
  const float* iw   = (const float*)d_in[10];
  const float* ib   = (const float*)d_in[11];
  const float* wihf = (const float*)d_in[12];
  const float* whhf = (const float*)d_in[13];
  const float* bihf = (const float*)d_in[14];
  const float* bhhf = (const float*)d_in[15];
  const float* wihb = (const float*)d_in[16];
  const float* whhb = (const float*)d_in[17];
  const float* bihb = (const float*)d_in[18];
  const float* bhhb = (const float*)d_in[19];
  const float* cw   = (const float*)d_in[20];
  const float* cb   = (const float*)d_in[21];
  float* out = (float*)d_out;

  char* ws = (char*)d_ws;
  __bf16* Aw32  = (__bf16*)(ws);                        //  0MB: 983 KB
  uint4* Wq     = (uint4*)(ws +  1u * 1024 * 1024);     //  1MB: 1 MB
  float* sent   = (float*)(ws +  2u * 1024 * 1024);     //  2MB: 2048*304*4 = 2.49 MB
  float* G      = (float*)(ws +  8u * 1024 * 1024);     //  8MB: 8 MB
  float* h0     = (float*)(ws + 16u * 1024 * 1024);     // 16MB: 128 KB
  float* H      = (float*)(ws + 17u * 1024 * 1024);     // 17MB: 8.4 MB (end ~26MB)

  prep_convw<<<1920, 256, 0, stream>>>(w3, w4, w5, Aw32);
  prep_whh<<<256, 256, 0, stream>>>(whhf, whhb, Wq);

  hipFuncSetAttribute(reinterpret_cast<const void*>(conv_kernel),
                      hipFuncAttributeMaxDynamicSharedMemorySize, LDSBYTES);
  conv_kernel<<<2048, 256, LDSBYTES, stream>>>(tok, emb, Aw32, b3, b4, b5, sent);

  xigh0_kernel<<<264, 256, 0, stream>>>(sent, pw, pb, wihf, wihb, bihf, bhhf, bihb, bhhb,
                                        iw, ib, G, h0);
  rnn_kernel<<<128, 256, 0, stream>>>(Wq, G, h0, H);
  pred_kernel<<<2048, 64, 0, stream>>>(H, cw, cb, out);
}